// Round 8
// baseline (445.753 us; speedup 1.0000x reference)
//
#include <hip/hip_runtime.h>

// Correlation volume, N=8, Z=128, H=W=160, 81 shifts (9 dy x 9 dx).
// v8 = r7 (ZC=2, NBUF=4/distance-3, 1 global_load_lds/thread/prefetch,
// 800 blocks of 9 waves, bid%8 = image -> XCD, __launch_bounds__(576,4))
// with ONE change: lane remap 8r x 8g(C=4) -> 2z' x 8r x 4g(C=8).
// Each lane handles its z-parity only: 6 LDS reads per 72 FMAs instead of
// 8 per 72 (-25% LDS-pipe instructions, the 75%-busy pipe per r7 budget).
// Parity partials are combined by one shfl_xor(32)+add pass in the epilogue.
#define NB 8
#define ZD 128
#define HD 160
#define WD 160
#define PLANE (HD * WD)            // 25600
#define IMG (ZD * PLANE)

#define TI 8
#define TJ 32
#define COLT 5                     // col tiles; 20 row tiles -> 100 tiles/img
#define NTHREADS 576               // 9 waves; wave w = dy index
#define ZC 2
#define NCHUNK (ZD / ZC)           // 64

#define ASL 9                      // A 16B-slots/row (8 data + 1 pad)
#define BSL 11                     // B 16B-slots/row (10 data + 1 pad)
#define BROWS 16                   // B row window (8 + 8 halo)
#define A_SLOTS (ZC * TI * ASL)    // 144
#define B_SLOTS (ZC * BROWS * BSL) // 352
#define REAL_SLOTS (A_SLOTS + B_SLOTS) // 496
#define BUF_SLOTS 512              // padded; slots >= 496 are dead pad
#define NBUF 4                     // prefetch distance 3

#define GP(x) ((const __attribute__((address_space(1))) void*)(x))
#define LP(x) ((__attribute__((address_space(3))) void*)(x))

__global__ __launch_bounds__(NTHREADS, 4)
void corr_vol_kernel(const float* __restrict__ A, const float* __restrict__ B,
                     const float* __restrict__ zp, float* __restrict__ out) {
    __shared__ float4 lds[NBUF * BUF_SLOTS];   // 32 KB
    __shared__ float4 dump[64];                // sink for wave-8 / tail dummies

    const int tid = threadIdx.x;
    const int bid = blockIdx.x;
    const int n  = bid & 7;            // XCD = image
    const int s  = bid >> 3;           // tile 0..99
    const int it = s / COLT, jt = s - COLT * it;
    const int i0 = it * TI, j0 = jt * TJ;

    const float* Abase = A + (size_t)n * IMG;
    const float* Bbase = B + (size_t)n * IMG;

    // ---- staging descriptor: slot = tid (A [0,144), B [144,496), pad/dummy) ----
    // IDENTICAL to r7.
    const float* p; int st;
    if (tid < A_SLOTS) {
        const int zA = tid / (TI * ASL), rem = tid % (TI * ASL);
        const int rA = rem / ASL, cA = rem % ASL;
        const bool v = (cA < 8);
        p = v ? Abase + (size_t)zA * PLANE + (size_t)(i0 + rA) * WD + (j0 + 4 * cA) : zp;
        st = v ? ZC * PLANE : 0;
    } else if (tid < REAL_SLOTS) {
        const int q = tid - A_SLOTS;
        const int zB = q / (BROWS * BSL), rem = q % (BROWS * BSL);
        const int rB = rem / BSL, cB = rem % BSL;
        const int gr = i0 - 4 + rB, gc = j0 - 4 + 4 * cB;
        const bool v = (cB < 10) && ((unsigned)gr < (unsigned)HD) &&
                       ((unsigned)gc < (unsigned)WD);
        p = v ? Bbase + (size_t)zB * PLANE + (size_t)gr * WD + gc : zp;
        st = v ? ZC * PLANE : 0;
    } else {                           // pad slots 496..511 and wave 8
        p = zp; st = 0;
    }
    const bool in_buf = (tid < BUF_SLOTS);            // wave-uniform (512 = 8*64)
    const unsigned dslot = (unsigned)(tid & ~63);     // wave-uniform slot base
    const float* pp = p;

    // Exactly 1 global_load_lds per thread per prefetch -> exact vmcnt math.
    auto prefetch = [&](int k2, int pb) {
        char* base = (char*)&lds[pb * BUF_SLOTS];
        if (k2 < NCHUNK) {
            __builtin_amdgcn_global_load_lds(GP(pp),
                LP(in_buf ? base + 16u * dslot : (char*)&dump[0]), 16, 0, 0);
            pp += st;
        } else {  // tail dummy keeps per-wave outstanding-count uniform
            __builtin_amdgcn_global_load_lds(GP(zp), LP((char*)&dump[0]), 16, 0, 0);
        }
    };

    // ---- compute lane map: 2 z-parities x 8 rows x 4 col-groups (8 cols) ----
    const int w = tid >> 6;            // dy index 0..8
    const int l = tid & 63;
    const int zpar = l >> 5;           // z-parity 0/1 (which z of the chunk)
    const int h = l & 31;
    const int r = h >> 2;              // pixel row 0..7
    const int g = h & 3;               // col group (8 cols each)

    // LDS float offsets (constant per thread)
    const int aoff = zpar * (TI * ASL * 4) + ASL * 4 * r + 8 * g;
    const int boff = zpar * (BROWS * BSL * 4) + BSL * 4 * (r + w) + 8 * g;

    float acc[9][8];
    #pragma unroll
    for (int d = 0; d < 9; ++d)
        #pragma unroll
        for (int q = 0; q < 8; ++q) acc[d][q] = 0.f;

    prefetch(0, 0);
    prefetch(1, 1);
    prefetch(2, 2);

#define STEP(k, rb, pb) do {                                                    \
    asm volatile("s_waitcnt vmcnt(2)\n\ts_barrier" ::: "memory");               \
    prefetch((k) + 3, (pb));                                                    \
    const float* Af = (const float*)&lds[(rb) * BUF_SLOTS];                     \
    const float* az = Af + aoff;                                                \
    const float* bz = Af + 4 * A_SLOTS + boff;                                  \
    float a[8], b[16];                                                          \
    *(float4*)&a[0]  = *(const float4*)(az);                                    \
    *(float4*)&a[4]  = *(const float4*)(az + 4);                                \
    *(float4*)&b[0]  = *(const float4*)(bz);                                    \
    *(float4*)&b[4]  = *(const float4*)(bz + 4);                                \
    *(float4*)&b[8]  = *(const float4*)(bz + 8);                                \
    *(float4*)&b[12] = *(const float4*)(bz + 12);                               \
    _Pragma("unroll")                                                           \
    for (int d = 0; d < 9; ++d)                                                 \
        _Pragma("unroll")                                                       \
        for (int q = 0; q < 8; ++q)                                             \
            acc[d][q] = fmaf(a[q], b[q + d], acc[d][q]);                        \
} while (0)

    for (int m = 0; m < NCHUNK / 4; ++m) {
        const int k = 4 * m;
        STEP(k + 0, 0, 3);
        STEP(k + 1, 1, 0);
        STEP(k + 2, 2, 1);
        STEP(k + 3, 3, 2);
    }
#undef STEP

    asm volatile("s_waitcnt vmcnt(0)" ::: "memory");  // drain tail dummies

    // ---- combine z-parity partials: lane l and l^32 hold the same outputs ----
    #pragma unroll
    for (int d = 0; d < 9; ++d)
        #pragma unroll
        for (int q = 0; q < 8; ++q)
            acc[d][q] += __shfl_xor(acc[d][q], 32, 64);

    // ---- epilogue: out[k = d*9 + w]; parity halves split the d-range ----
    #pragma unroll
    for (int d = 0; d < 9; ++d) {
        if ((zpar == 0) ? (d < 4) : (d >= 4)) {     // uniform per half-wave
            const int kk = d * 9 + w;
            float* o = out + (((size_t)(n * 81 + kk)) * HD + (i0 + r)) * WD + j0 + 8 * g;
            *(float4*)&o[0] = make_float4(acc[d][0], acc[d][1], acc[d][2], acc[d][3]);
            *(float4*)&o[4] = make_float4(acc[d][4], acc[d][5], acc[d][6], acc[d][7]);
        }
    }
}

extern "C" void kernel_launch(void* const* d_in, const int* in_sizes, int n_in,
                              void* d_out, int out_size, void* d_ws, size_t ws_size,
                              hipStream_t stream) {
    const float* A = (const float*)d_in[0];
    const float* B = (const float*)d_in[1];
    float* out = (float*)d_out;
    // 256 B zero page for OOB/pad staging lanes (d_ws re-poisoned every launch).
    hipMemsetAsync(d_ws, 0, 256, stream);
    corr_vol_kernel<<<dim3(NB * 100), dim3(NTHREADS), 0, stream>>>(
        A, B, (const float*)d_ws, out);
}

// Round 9
// 299.390 us; speedup vs baseline: 1.4889x; 1.4889x over previous
//
#include <hip/hip_runtime.h>

// Correlation volume, N=8, Z=128, H=W=160, 81 shifts (9 dy x 9 dx).
// v9 = r7's proven per-lane shape (C=4, acc[9][4]=36 regs, ZC=2,
// NBUF=4/distance-3, counted-vmcnt staging) re-packed into 3-wave blocks:
// block = (8x32 tile, dy-triple), 192 thr, 2400 blocks (9.4/CU), 6
// independent barrier-domains/CU instead of 3, 3-wave barrier convergence
// instead of 9. B is staged per-triple (10 rows vs 16) -> more staging
// traffic, bought for independence. r3 already showed this decomposition
// but spilled (WRITE 229 MB, acc[9][8]); per-lane state here is r7's lean
// config under the never-spilled (.,4) bound. dq varies fastest so a
// tile's 3 triples co-schedule and share the A tile in L2.
#define NB 8
#define ZD 128
#define HD 160
#define WD 160
#define PLANE (HD * WD)            // 25600
#define IMG (ZD * PLANE)

#define TI 8
#define TJ 32
#define COLT 5                     // 20 row-tiles x 5 col-tiles = 100 tiles/img
#define NTHREADS 192               // 3 waves; wave wi = dy within triple
#define ZC 2
#define NCHUNK (ZD / ZC)           // 64

#define ASL 9                      // A 16B-slots/row (8 data + 1 pad)
#define BSL 11                     // B 16B-slots/row (10 data + 1 pad)
#define BROWSB 10                  // B row window for a triple (8 + 2span/halo)
#define A_SLOTS (ZC * TI * ASL)    // 144
#define B_SLOTS (ZC * BROWSB * BSL)// 220
#define REAL_SLOTS (A_SLOTS + B_SLOTS) // 364
#define BUF_SLOTS 384              // = 2*NTHREADS; slots >= 364 are dead pad
#define NBUF 4                     // prefetch distance 3

#define GP(x) ((const __attribute__((address_space(1))) void*)(x))
#define LP(x) ((__attribute__((address_space(3))) void*)(x))

__global__ __launch_bounds__(NTHREADS, 4)
void corr_vol_kernel(const float* __restrict__ A, const float* __restrict__ B,
                     const float* __restrict__ zp, float* __restrict__ out) {
    __shared__ float4 lds[NBUF * BUF_SLOTS];   // 24.6 KB
    __shared__ float4 dump[64];                // sink for tail dummy loads

    const int tid = threadIdx.x;
    const int bid = blockIdx.x;
    const int n  = bid & 7;            // XCD = image
    const int s  = bid >> 3;           // 0..299
    const int tl = s / 3;              // tile 0..99
    const int dq = s - 3 * tl;         // dy-triple 0..2
    const int it = tl / COLT, jt = tl - COLT * it;
    const int i0 = it * TI, j0 = jt * TJ;

    const float* Abase = A + (size_t)n * IMG;
    const float* Bbase = B + (size_t)n * IMG;

    // ---- staging descriptor for LDS slot: A [0,144), B [144,364), pad ----
    auto decode = [&](int slot, const float*& p, int& st) {
        if (slot < A_SLOTS) {
            const int zA = slot / (TI * ASL), rem = slot % (TI * ASL);
            const int rA = rem / ASL, cA = rem % ASL;
            const bool v = (cA < 8);
            p = v ? Abase + (size_t)zA * PLANE + (size_t)(i0 + rA) * WD + (j0 + 4 * cA) : zp;
            st = v ? ZC * PLANE : 0;
        } else if (slot < REAL_SLOTS) {
            const int q = slot - A_SLOTS;
            const int zB = q / (BROWSB * BSL), rem = q % (BROWSB * BSL);
            const int rB = rem / BSL, cB = rem % BSL;
            const int gr = i0 + 3 * dq - 4 + rB, gc = j0 - 4 + 4 * cB;
            const bool v = (cB < 10) && ((unsigned)gr < (unsigned)HD) &&
                           ((unsigned)gc < (unsigned)WD);
            p = v ? Bbase + (size_t)zB * PLANE + (size_t)gr * WD + gc : zp;
            st = v ? ZC * PLANE : 0;
        } else {                       // dead-pad slots 364..383
            p = zp; st = 0;
        }
    };

    const float *p1, *p2; int st1, st2;
    decode(tid, p1, st1);                        // slot1 = tid        (< 384)
    decode(tid + NTHREADS, p2, st2);             // slot2 = tid + 192  (< 384)
    const unsigned d1 = (unsigned)(tid & ~63);               // wave-uniform
    const unsigned d2 = (unsigned)((tid + NTHREADS) & ~63);  // wave-uniform
    const float* pp1 = p1;
    const float* pp2 = p2;

    // Exactly 2 global_load_lds per thread per prefetch -> exact vmcnt math.
    auto prefetch = [&](int k2, int pb) {
        char* base = (char*)&lds[pb * BUF_SLOTS];
        if (k2 < NCHUNK) {
            __builtin_amdgcn_global_load_lds(GP(pp1), LP(base + 16u * d1), 16, 0, 0);
            __builtin_amdgcn_global_load_lds(GP(pp2), LP(base + 16u * d2), 16, 0, 0);
            pp1 += st1; pp2 += st2;
        } else {  // tail dummies keep per-wave outstanding-count uniform
            __builtin_amdgcn_global_load_lds(GP(zp), LP((char*)&dump[0]), 16, 0, 0);
            __builtin_amdgcn_global_load_lds(GP(zp), LP((char*)&dump[0]), 16, 0, 0);
        }
    };

    // ---- compute lane map (r7's): 8 rows x 8 col-groups (C=4) ----
    const int wi = tid >> 6;           // 0..2 within triple
    const int w  = 3 * dq + wi;        // dy index 0..8
    const int l  = tid & 63;
    const int r  = l >> 3;             // pixel row 0..7
    const int g  = l & 7;              // col group (4 cols each)

    // LDS float offsets (constant per thread)
    const int aoff = ASL * 4 * r + 4 * g;                  // within A z-slice
    const int boff = BSL * 4 * (r + wi) + 4 * g;           // within B z-slice

    float acc[9][4];
    #pragma unroll
    for (int d = 0; d < 9; ++d)
        #pragma unroll
        for (int q = 0; q < 4; ++q) acc[d][q] = 0.f;

    prefetch(0, 0);
    prefetch(1, 1);
    prefetch(2, 2);

#define STEP(k, rb, pb) do {                                                    \
    asm volatile("s_waitcnt vmcnt(4)\n\ts_barrier" ::: "memory");               \
    prefetch((k) + 3, (pb));                                                    \
    const float* Af = (const float*)&lds[(rb) * BUF_SLOTS];                     \
    _Pragma("unroll")                                                           \
    for (int z = 0; z < ZC; ++z) {                                              \
        const float* az = Af + z * (TI * ASL * 4) + aoff;                       \
        const float* bz = Af + 4 * A_SLOTS + z * (BROWSB * BSL * 4) + boff;     \
        float a[4], b[12];                                                      \
        *(float4*)&a[0] = *(const float4*)(az);                                 \
        *(float4*)&b[0] = *(const float4*)(bz);                                 \
        *(float4*)&b[4] = *(const float4*)(bz + 4);                             \
        *(float4*)&b[8] = *(const float4*)(bz + 8);                             \
        _Pragma("unroll")                                                       \
        for (int d = 0; d < 9; ++d)                                             \
            _Pragma("unroll")                                                   \
            for (int q = 0; q < 4; ++q)                                         \
                acc[d][q] = fmaf(a[q], b[q + d], acc[d][q]);                    \
    }                                                                           \
} while (0)

    for (int m = 0; m < NCHUNK / 4; ++m) {
        const int k = 4 * m;
        STEP(k + 0, 0, 3);
        STEP(k + 1, 1, 0);
        STEP(k + 2, 2, 1);
        STEP(k + 3, 3, 2);
    }
#undef STEP

    asm volatile("s_waitcnt vmcnt(0)" ::: "memory");  // drain tail dummies

    // ---- epilogue: out[k = d*9 + w] (d = x-shift, w = y-shift) ----
    #pragma unroll
    for (int d = 0; d < 9; ++d) {
        const int kk = d * 9 + w;
        float* o = out + (((size_t)(n * 81 + kk)) * HD + (i0 + r)) * WD + j0 + 4 * g;
        *(float4*)o = make_float4(acc[d][0], acc[d][1], acc[d][2], acc[d][3]);
    }
}

extern "C" void kernel_launch(void* const* d_in, const int* in_sizes, int n_in,
                              void* d_out, int out_size, void* d_ws, size_t ws_size,
                              hipStream_t stream) {
    const float* A = (const float*)d_in[0];
    const float* B = (const float*)d_in[1];
    float* out = (float*)d_out;
    // 256 B zero page for OOB/pad staging lanes (d_ws re-poisoned every launch).
    hipMemsetAsync(d_ws, 0, 256, stream);
    corr_vol_kernel<<<dim3(NB * 100 * 3), dim3(NTHREADS), 0, stream>>>(
        A, B, (const float*)d_ws, out);
}